// Round 6
// baseline (153.282 us; speedup 1.0000x reference)
//
#include <hip/hip_runtime.h>

#define HH 512
#define WW 512
#define PD 544                          // 512 + 2*16
#define PADN (3 * PD * PD)              // padded elements per 3 channels
#define OUTN (3 * HH * WW)
#define NB 128
#define KSTR 16384                      // 128*128 floats between taps

typedef float f2 __attribute__((ext_vector_type(2)));

// ---------------- pad + out-zero: fp32 img -> fp32 edge-padded ----------------
__global__ __launch_bounds__(256) void pad_f32(const float* __restrict__ img,
                                               float* __restrict__ gpad,
                                               float* __restrict__ out) {
    int idx = blockIdx.x * 256 + threadIdx.x;
    if (idx < OUTN) out[idx] = 0.0f;           // zero the atomic target
    if (idx >= PADN) return;
    int c  = idx / (PD * PD);
    int r  = idx - c * (PD * PD);
    int py = r / PD;
    int px = r - py * PD;
    int iy = min(max(py - 16, 0), HH - 1);
    int ix = min(max(px - 16, 0), WW - 1);
    gpad[idx] = img[(c * HH + iy) * WW + ix];
}

// ---------------- pad + out-zero: fp32 img -> bf16 edge-padded (fallback) -----
__global__ __launch_bounds__(256) void pad_bf16(const float* __restrict__ img,
                                                unsigned short* __restrict__ gpad,
                                                float* __restrict__ out) {
    int idx = blockIdx.x * 256 + threadIdx.x;
    if (idx < OUTN) out[idx] = 0.0f;
    if (idx >= PADN) return;
    int c  = idx / (PD * PD);
    int r  = idx - c * (PD * PD);
    int py = r / PD;
    int px = r - py * PD;
    int iy = min(max(py - 16, 0), HH - 1);
    int ix = min(max(px - 16, 0), WW - 1);
    union { float f; unsigned u; } v;
    v.f = img[(c * HH + iy) * WW + ix];
    unsigned u = v.u + 0x7FFFu + ((v.u >> 16) & 1u);   // RNE bf16
    gpad[idx] = (unsigned short)(u >> 16);
}

// ---- async global->LDS (wave-uniform LDS base; HW puts lane i at base+i*size) ----
__device__ __forceinline__ void async16f(const float* g, float* l) {
    __builtin_amdgcn_global_load_lds((const __attribute__((address_space(1))) void*)g,
                                     (__attribute__((address_space(3))) void*)l, 16, 0, 0);
}
__device__ __forceinline__ void async4f(const float* g, float* l) {
    __builtin_amdgcn_global_load_lds((const __attribute__((address_space(1))) void*)g,
                                     (__attribute__((address_space(3))) void*)l, 4, 0, 0);
}
__device__ __forceinline__ void async16u(const unsigned short* g, unsigned short* l) {
    __builtin_amdgcn_global_load_lds((const __attribute__((address_space(1))) void*)g,
                                     (__attribute__((address_space(3))) void*)l, 16, 0, 0);
}
__device__ __forceinline__ float bflo(unsigned d) { union { unsigned u; float f; } x; x.u = d << 16;         return x.f; }
__device__ __forceinline__ float bfhi(unsigned d) { union { unsigned u; float f; } x; x.u = d & 0xFFFF0000u; return x.f; }

// ---------------- main kernel (fp32 image, LDS-staged weights) ----------------
// ROUND 12: WEIGHTS VIA LDS. Rounds 0-5 exonerated VALU issue (cut 40%, no
// change), LDS conflicts (0), occupancy (2 vs 4 blk/CU tie), barriers
// (barrier-free tie), HBM BW (18%). Invariant across all: 33 per-lane global
// weight loads per iter consumed straight by the FMA chain. Round-5 tells:
// VGPR=52 -> compiler recycles registers across the 33 loads = SEVERAL
// serialized L2/HBM round-trips per iteration (~4x900cy ~= the observed
// ~4000cy/iter stall); FETCH 46MB ~= the 71MB weight tensor (real HBM
// misses). Fix: stage weights global->LDS with async4 (no dest VGPRs), one
// full iteration ahead, double-buffered s_w[2][33*64] (16.9KB). Weights are
// dy-uniform: the 4 waves split the 33 taps (v%4==dy, 8-9 async4 each;
// dest = &s_w[buf][v*64], 64 lanes x 4B = one 256B tap slice). Consume via
// 33 conflict-free ds_read_b32 (~120cy, hidden under unpack/FMA). Also cuts
// weight VMEM instrs per block-iter 132 -> 33 and the 4x per-wave redundancy.
// LDS 27.6+16.9 = 44.5KB -> 3 blocks/CU. Everything else as round 11
// (fp32 image ring, f2 pk-FMA, per-iter vmcnt(0)+s_barrier, 4 u-chunks,
// atomicAdd combine).
__global__ __launch_bounds__(256, 2) void reblur_f32(const float* __restrict__ gpad,
                                                     const float* __restrict__ Kern,
                                                     float* __restrict__ out) {
    __shared__ float s_img[8][3][288];            // 27648 B, ring over padded rows
    __shared__ float s_w[2][33 * 64];             // 16896 B, weight double-buffer

    const int lane = threadIdx.x & 63;
    const int dy   = threadIdx.x >> 6;            // wave id 0..3
    const int uq   = blockIdx.x >> 8;             // u-chunk 0..3
    const int bb   = blockIdx.x & 255;
    const int h    = bb >> 1;                     // 0..127
    const int wt   = bb & 1;                      // 0..1
    const int ua   = uq ? (8 * uq + 1) : 0;       // chunk start u: 0,9,17,25
    const int n    = uq ? 8 : 9;                  // chunk length (sums to 33)
    const int kb   = h * NB + wt * 64;            // uniform weight dword base

    // ---- prologue: image row 4h+ua+dy (x3c) + weights for t=0 into buf 0 ----
    {
        const int r = 4 * h + ua + dy;
#pragma unroll
        for (int c = 0; c < 3; ++c) {
            const float* gp = gpad + (size_t)(c * PD + r) * PD + 256 * wt;
            async16f(gp + 4 * lane, &s_img[r & 7][c][0]);
            if (lane < 8)
                async16f(gp + 256 + 4 * lane, &s_img[r & 7][c][256]);
        }
    }
#pragma unroll 1
    for (int v = dy; v < 33; v += 4)
        async4f(Kern + (size_t)(ua * 33 + v) * KSTR + kb + lane, &s_w[0][v * 64]);

    f2 accL[3], accH[3];                          // (oj0,oj1) and (oj2,oj3)
#pragma unroll
    for (int c = 0; c < 3; ++c) { accL[c] = (f2)(0.0f); accH[c] = (f2)(0.0f); }

#pragma unroll 1
    for (int t = 0; t < n; ++t) {
        // all prior global_load_lds (image rows + weight slices) have landed
        asm volatile("s_waitcnt vmcnt(0)" ::: "memory");
        __builtin_amdgcn_s_barrier();

        // stage weights for t+1 into the other buffer (4 waves split taps)
        if (t + 1 < n) {
            const int un = ua + t + 1;
            float* wdst = &s_w[(t + 1) & 1][0];
#pragma unroll 1
            for (int v = dy; v < 33; v += 4)
                async4f(Kern + (size_t)(un * 33 + v) * KSTR + kb + lane, wdst + v * 64);

            // stage padded image row for iteration t+1 (row 4h+ua+t+4)
            if (dy == (t & 3)) {
                const int r = 4 * h + ua + t + 4;
#pragma unroll
                for (int c = 0; c < 3; ++c) {
                    const float* gp = gpad + (size_t)(c * PD + r) * PD + 256 * wt;
                    async16f(gp + 4 * lane, &s_img[r & 7][c][0]);
                    if (lane < 8)
                        async16f(gp + 256 + 4 * lane, &s_img[r & 7][c][256]);
                }
            }
        }

        const int   slot = (4 * h + ua + t + dy) & 7;
        const float* wrow = &s_w[t & 1][lane];     // lane's dword of each tap
#pragma unroll
        for (int c = 0; c < 3; ++c) {
            float wf[36];
            const float4* sp = (const float4*)&s_img[slot][c][4 * lane];
#pragma unroll
            for (int j = 0; j < 9; ++j) {
                const float4 rr = sp[j];           // ds_read_b128
                wf[4 * j + 0] = rr.x;
                wf[4 * j + 1] = rr.y;
                wf[4 * j + 2] = rr.z;
                wf[4 * j + 3] = rr.w;
            }
            f2 aL = accL[c], aH = accH[c];
#pragma unroll
            for (int v = 0; v < 33; ++v) {
                const float w = wrow[v * 64];      // ds_read_b32, conflict-free
                const f2 w2 = {w, w};
                const f2 xl = {wf[v + 0], wf[v + 1]};
                const f2 xh = {wf[v + 2], wf[v + 3]};
                aL = xl * w2 + aL;                 // -> v_pk_fma_f32
                aH = xh * w2 + aH;
            }
            accL[c] = aL; accH[c] = aH;
        }
    }

    // ---- epilogue: 4 u-chunks accumulate into the pad-zeroed output ----
    const int xb = 4 * (wt * 64 + lane);
#pragma unroll
    for (int c = 0; c < 3; ++c) {
        float* op = out + (size_t)(c * HH + 4 * h + dy) * WW + xb;
        atomicAdd(op + 0, accL[c].x);
        atomicAdd(op + 1, accL[c].y);
        atomicAdd(op + 2, accH[c].x);
        atomicAdd(op + 3, accH[c].y);
    }
}

// ---------------- bf16 fallback kernel (round-4 structure, proven) ----------
__global__ __launch_bounds__(256, 2) void reblur_bf16(const unsigned short* __restrict__ gpad,
                                                      const float* __restrict__ Kern,
                                                      float* __restrict__ out) {
    __shared__ unsigned short s_img[4][4][3][288];

    const int lane = threadIdx.x & 63;
    const int dy   = threadIdx.x >> 6;
    const int uq   = blockIdx.x >> 8;
    const int bb   = blockIdx.x & 255;
    const int h    = bb >> 1;
    const int wt   = bb & 1;
    const int ua   = uq ? (8 * uq + 1) : 0;
    const int n    = uq ? 8 : 9;
    const int kofs = h * NB + wt * 64 + lane;
    const int y    = 4 * h + dy;

    if (lane < 36) {
#pragma unroll
        for (int p = 0; p < 3; ++p)
#pragma unroll
            for (int c = 0; c < 3; ++c)
                async16u(gpad + ((size_t)(c * PD + y + ua + p) * PD + 256 * wt) + 8 * lane,
                         &s_img[dy][p][c][0]);
    }

    float acc[3][4];
#pragma unroll
    for (int c = 0; c < 3; ++c)
#pragma unroll
        for (int oj = 0; oj < 4; ++oj) acc[c][oj] = 0.0f;

#pragma unroll 1
    for (int t = 0; t < n; ++t) {
        asm volatile("s_waitcnt lgkmcnt(0)" ::: "memory");
        if (t + 3 < n && lane < 36) {
            const int r = y + ua + t + 3;
#pragma unroll
            for (int c = 0; c < 3; ++c)
                async16u(gpad + ((size_t)(c * PD + r) * PD + 256 * wt) + 8 * lane,
                         &s_img[dy][(t + 3) & 3][c][0]);
        }
        asm volatile("s_waitcnt vmcnt(3)" ::: "memory");
        __builtin_amdgcn_sched_barrier(0);

        float wA[33];
#pragma unroll
        for (int v = 0; v < 33; ++v)
            wA[v] = Kern[(size_t)((ua + t) * 33 + v) * KSTR + kofs];

        const int slot = t & 3;
#pragma unroll
        for (int c = 0; c < 3; ++c) {
            float wf[36];
            const unsigned short* sp = &s_img[dy][slot][c][4 * lane];
#pragma unroll
            for (int j = 0; j < 9; ++j) {
                const uint2 dd = *(const uint2*)(sp + 4 * j);
                wf[4 * j + 0] = bflo(dd.x);
                wf[4 * j + 1] = bfhi(dd.x);
                wf[4 * j + 2] = bflo(dd.y);
                wf[4 * j + 3] = bfhi(dd.y);
            }
#pragma unroll
            for (int v = 0; v < 33; ++v) {
#pragma unroll
                for (int oj = 0; oj < 4; ++oj)
                    acc[c][oj] = fmaf(wf[v + oj], wA[v], acc[c][oj]);
            }
        }
    }

    const int xb = 4 * (wt * 64 + lane);
#pragma unroll
    for (int c = 0; c < 3; ++c) {
        float* op = out + (size_t)(c * HH + y) * WW + xb;
#pragma unroll
        for (int oj = 0; oj < 4; ++oj) atomicAdd(op + oj, acc[c][oj]);
    }
}

// ---------------- fallback (ws too small): naive but correct ----------------
__global__ __launch_bounds__(256) void reblur_naive(const float* __restrict__ img,
                                                    const float* __restrict__ Kern,
                                                    float* __restrict__ out) {
    const int lane = threadIdx.x & 63;
    const int dy   = threadIdx.x >> 6;
    const int c    = blockIdx.x >> 8;
    const int bb   = blockIdx.x & 255;
    const int h    = bb >> 1;
    const int wt   = bb & 1;
    const int wb   = wt * 64 + lane;
    const int y    = 4 * h + dy;

    float acc[4] = {0.f, 0.f, 0.f, 0.f};
    const float* kb = Kern + h * NB + wb;
#pragma unroll 1
    for (int u = 0; u < 33; ++u) {
        const int iy = min(max(y + u - 16, 0), HH - 1);
        float row[36];
#pragma unroll
        for (int e = 0; e < 36; ++e) {
            const int ix = min(max(4 * wb + e - 16, 0), WW - 1);
            row[e]       = img[(c * HH + iy) * WW + ix];
        }
#pragma unroll
        for (int v = 0; v < 33; ++v) {
            const float w = kb[(u * 33 + v) * KSTR];
#pragma unroll
            for (int oj = 0; oj < 4; ++oj)
                acc[oj] = fmaf(row[v + oj], w, acc[oj]);
        }
    }
    float4 o;
    o.x = acc[0]; o.y = acc[1]; o.z = acc[2]; o.w = acc[3];
    *reinterpret_cast<float4*>(out + (size_t)(c * HH + y) * WW + 4 * wb) = o;
}

extern "C" void kernel_launch(void* const* d_in, const int* in_sizes, int n_in,
                              void* d_out, int out_size, void* d_ws, size_t ws_size,
                              hipStream_t stream) {
    const float* img  = (const float*)d_in[0];
    const float* Kern = (const float*)d_in[1];
    float* out        = (float*)d_out;

    if (ws_size >= (size_t)PADN * sizeof(float)) {
        float* gpad = (float*)d_ws;
        pad_f32<<<(PADN + 255) / 256, 256, 0, stream>>>(img, gpad, out);
        reblur_f32<<<1024, 256, 0, stream>>>(gpad, Kern, out);
    } else if (ws_size >= (size_t)PADN * sizeof(unsigned short)) {
        unsigned short* gpad = (unsigned short*)d_ws;
        pad_bf16<<<(PADN + 255) / 256, 256, 0, stream>>>(img, gpad, out);
        reblur_bf16<<<1024, 256, 0, stream>>>(gpad, Kern, out);
    } else {
        reblur_naive<<<768, 256, 0, stream>>>(img, Kern, out);
    }
}